// Round 1
// baseline (714.232 us; speedup 1.0000x reference)
//
#include <hip/hip_runtime.h>
#include <hip/hip_fp16.h>

// QNetGNN: 2-layer GCN, N=100000, E=3.2M, F: 128 -> 16 -> 32.
// R12: push-style aggregation. k_csr (per-node CSR build) is GONE; the
// gather's dependent rowptr->csr->feature load chain is GONE. Edges stay
// bucket-sorted (k_coarse/k_scan/k_bin); k_agg takes one block per bucket,
// accumulates into an LDS fp32 accumulator (stride 17 vs bank conflicts)
// with ds_add_f32, reading edges coalesced and feature rows (fp16, 32B,
// L2-resident) independently. Buckets are 196 nodes (NB=511 ~= 2 blocks/CU,
// magic-multiply division) to kill the 392-block tail imbalance.
// featp = fp16(x@W1 * dis) pre-scaled by source norm; h1p likewise.

#define NNODES 100000
#define FIN    128
#define FHID   16
#define NACT   32
#define BUCK   196          // nodes per bucket (non-pow2 -> 511 blocks balance on 256 CUs)
#define NB     511          // ceil(100000/196)
#define MAGIC  21913099u    // ceil(2^32/196); (d*MAGIC)>>32 == d/196 for d < 39.7M
#define TILE   4096
#define ASTRIDE 17          // LDS accumulator row stride (odd -> spreads ds_add banks)

__device__ __forceinline__ int bucket_of(int d) {
    return (int)__umulhi((unsigned)d, MAGIC);
}

__device__ __forceinline__ unsigned pack2(float a, float b) {
    __half2 h = __floats2half2_rn(a, b);
    return *reinterpret_cast<unsigned*>(&h);
}

__device__ __forceinline__ float2 h2f(unsigned u) {
    return __half22float2(*reinterpret_cast<__half2*>(&u));
}

// ---- coarse histogram of dst buckets; also store per-tile hist (ushort) ----
__global__ void k_coarse(const int* __restrict__ dst, int E, int* __restrict__ bcnt,
                         unsigned short* __restrict__ thist) {
    __shared__ int hist[NB];
    int t = threadIdx.x;
    int tb = blockIdx.x * TILE;
    int tn = min(TILE, E - tb);
    for (int i = t; i < NB; i += 256) hist[i] = 0;
    __syncthreads();
    for (int i = t; i < tn; i += 256) atomicAdd(&hist[bucket_of(dst[tb + i])], 1);
    __syncthreads();
    size_t row = (size_t)blockIdx.x * NB;
    for (int i = t; i < NB; i += 256) {
        int hv = hist[i];
        thist[row + i] = (unsigned short)hv;
        if (hv) atomicAdd(&bcnt[i], hv);
    }
}

// ---- exclusive scan of bcnt -> bptr[0..NB], init gcur (512 thr, NB<=512) ----
__global__ void __launch_bounds__(512) k_scan(
        const int* __restrict__ bcnt, int* __restrict__ bptr,
        int* __restrict__ gcur) {
    __shared__ int part[512];
    int t = threadIdx.x;
    int c = (t < NB) ? bcnt[t] : 0;
    part[t] = c;
    __syncthreads();
    for (int d = 1; d < 512; d <<= 1) {
        int v = part[t];
        int add = (t >= d) ? part[t - d] : 0;
        __syncthreads();
        part[t] = v + add;
        __syncthreads();
    }
    int excl = t ? part[t - 1] : 0;
    if (t < NB) { bptr[t] = excl; gcur[t] = excl; }
    if (t == NB) bptr[NB] = excl;      // total (c==0 for t>=NB)
}

// ---- bin: staged LDS counting sort, precomputed global dests, 512 thr ----
__global__ void __launch_bounds__(512) k_bin(
        const int* __restrict__ src, const int* __restrict__ dst, int E,
        int* __restrict__ gcur, const unsigned short* __restrict__ thist,
        unsigned* __restrict__ binned) {
    __shared__ unsigned staged[TILE];     // 16 KB
    __shared__ int gscat[TILE];           // 16 KB
    __shared__ int lstart[NB + 1];
    __shared__ int lcur[NB];
    __shared__ int gbase[NB];
    __shared__ int part[512];
    int t = threadIdx.x;
    int tb = blockIdx.x * TILE;
    int tn = min(TILE, E - tb);
    size_t row = (size_t)blockIdx.x * NB;
    int c = (t < NB) ? (int)thist[row + t] : 0;
    part[t] = c;
    __syncthreads();
    for (int d = 1; d < 512; d <<= 1) {
        int v = part[t];
        int add = (t >= d) ? part[t - d] : 0;
        __syncthreads();
        part[t] = v + add;
        __syncthreads();
    }
    int excl = t ? part[t - 1] : 0;
    if (t < NB) { lstart[t] = excl; lcur[t] = excl; }
    if (t == NB) lstart[NB] = excl;
    __syncthreads();
    if (t < NB) gbase[t] = (c > 0) ? atomicAdd(&gcur[t], c) : 0;
    __syncthreads();
    for (int i = t; i < tn; i += 512) {
        int d = dst[tb + i], sv = src[tb + i];
        int b = bucket_of(d);
        int pos = atomicAdd(&lcur[b], 1);
        staged[pos] = ((unsigned)sv << 8) | (unsigned)(d - b * BUCK);
        gscat[pos] = gbase[b] + (pos - lstart[b]);
    }
    __syncthreads();
    for (int j = t; j < tn; j += 512) binned[gscat[j]] = staged[j];
}

// ---- per-bucket degree count -> dis (needed before k_xw1 pre-scaling) ----
__global__ void k_deg(const int* __restrict__ bptr, const unsigned* __restrict__ binned,
                      float* __restrict__ dis, int n) {
    __shared__ int cnt[BUCK];
    int t = threadIdx.x;
    int bk = blockIdx.x;
    if (t < BUCK) cnt[t] = 0;
    __syncthreads();
    int beg = bptr[bk], end = bptr[bk + 1];
    for (int i = beg + t; i < end; i += 256) atomicAdd(&cnt[binned[i] & 255], 1);
    __syncthreads();
    int node = bk * BUCK + t;
    if (t < BUCK && node < n) dis[node] = rsqrtf((float)cnt[t] + 1.0f);
}

#define FMA4(A, S, W) { (A).x += (S) * (W).x; (A).y += (S) * (W).y; \
                        (A).z += (S) * (W).z; (A).w += (S) * (W).w; }

// ---- featp = fp16((x @ W1) * dis); row n = zeros ----
__global__ void k_xw1(const float* __restrict__ x, const float* __restrict__ W1,
                      const float* __restrict__ dis, __half* __restrict__ featp, int n) {
    __shared__ float w[FIN * FHID];   // 8 KB, row-major [128][16]
    for (int i = threadIdx.x; i < FIN * FHID; i += blockDim.x) w[i] = W1[i];
    __syncthreads();
    int r = blockIdx.x * blockDim.x + threadIdx.x;
    if (r > n) return;
    uint4* hr = (uint4*)(featp + (size_t)r * FHID);   // 32 B row = 2 uint4
    if (r == n) {
        uint4 z = make_uint4(0u, 0u, 0u, 0u);
        hr[0] = z; hr[1] = z;
        return;
    }
    const float4* xr = (const float4*)(x + (long long)r * FIN);
    const float4* w4 = (const float4*)w;      // [128][4] float4s
    float4 a0 = make_float4(0.f, 0.f, 0.f, 0.f), a1 = a0, a2 = a0, a3 = a0;
#pragma unroll 8
    for (int k4 = 0; k4 < FIN / 4; ++k4) {
        float4 xv = xr[k4];
        int kb = k4 * 16;
        FMA4(a0, xv.x, w4[kb + 0]);  FMA4(a1, xv.x, w4[kb + 1]);
        FMA4(a2, xv.x, w4[kb + 2]);  FMA4(a3, xv.x, w4[kb + 3]);
        FMA4(a0, xv.y, w4[kb + 4]);  FMA4(a1, xv.y, w4[kb + 5]);
        FMA4(a2, xv.y, w4[kb + 6]);  FMA4(a3, xv.y, w4[kb + 7]);
        FMA4(a0, xv.z, w4[kb + 8]);  FMA4(a1, xv.z, w4[kb + 9]);
        FMA4(a2, xv.z, w4[kb + 10]); FMA4(a3, xv.z, w4[kb + 11]);
        FMA4(a0, xv.w, w4[kb + 12]); FMA4(a1, xv.w, w4[kb + 13]);
        FMA4(a2, xv.w, w4[kb + 14]); FMA4(a3, xv.w, w4[kb + 15]);
    }
    float d = dis[r];
    uint4 w0, w1;
    w0.x = pack2(a0.x * d, a0.y * d); w0.y = pack2(a0.z * d, a0.w * d);
    w0.z = pack2(a1.x * d, a1.y * d); w0.w = pack2(a1.z * d, a1.w * d);
    w1.x = pack2(a2.x * d, a2.y * d); w1.y = pack2(a2.z * d, a2.w * d);
    w1.z = pack2(a3.x * d, a3.y * d); w1.w = pack2(a3.z * d, a3.w * d);
    hr[0] = w0; hr[1] = w1;
}

// ---- push aggregation: block per bucket, LDS fp32 acc, ds_add_f32 ----
// L==1: h1p = fp16(relu(di*acc + b1)*di)   [N,16]
// L==2: out = (di*acc) @ W2 + b2           [N,32] fp32 (W2 fused)
template <int L>
__global__ void __launch_bounds__(512) k_agg(
        const int* __restrict__ bptr, const unsigned* __restrict__ binned,
        const float* __restrict__ dis, const __half* __restrict__ featp,
        const float* __restrict__ W2, const float* __restrict__ bias,
        void* __restrict__ outp, int n) {
    __shared__ float acc[BUCK * ASTRIDE];    // 13.3 KB
    __shared__ float wb[FHID * NACT];
    __shared__ float bs[NACT];
    int t = threadIdx.x;
    int bk = blockIdx.x;
    int base = bk * BUCK;
    int nn = min(BUCK, n - base);
    const uint2* fp = (const uint2*)featp;   // 4 granules of 8 B per row
    if (L == 2) {
        for (int i = t; i < FHID * NACT; i += 512) wb[i] = W2[i];
        if (t < NACT) bs[t] = bias[t];
    }
    // init acc with the self-loop row (featp pre-scaled by dis[node])
    for (int idx = t; idx < BUCK * 4; idx += 512) {
        int d = idx >> 2, p = idx & 3;
        float2 f0 = make_float2(0.f, 0.f), f1 = f0;
        if (d < nn) {
            uint2 u = fp[(size_t)((base + d) << 2) + p];
            f0 = h2f(u.x); f1 = h2f(u.y);
        }
        float* a = &acc[d * ASTRIDE + p * 4];
        a[0] = f0.x; a[1] = f0.y; a[2] = f1.x; a[3] = f1.y;
    }
    __syncthreads();
    int beg = bptr[bk], end = bptr[bk + 1];
    int q = t >> 2, p = t & 3;               // quad of lanes per edge
    int i = beg + q;
    for (; i + 128 < end; i += 256) {        // 2 edges in flight per quad
        unsigned e0 = binned[i];
        unsigned e1 = binned[i + 128];
        uint2 u0 = fp[(size_t)((e0 >> 8) << 2) + p];
        uint2 u1 = fp[(size_t)((e1 >> 8) << 2) + p];
        float2 a0 = h2f(u0.x), b0 = h2f(u0.y);
        float2 a1 = h2f(u1.x), b1v = h2f(u1.y);
        float* d0 = &acc[(int)(e0 & 255) * ASTRIDE + p * 4];
        atomicAdd(d0 + 0, a0.x); atomicAdd(d0 + 1, a0.y);
        atomicAdd(d0 + 2, b0.x); atomicAdd(d0 + 3, b0.y);
        float* d1 = &acc[(int)(e1 & 255) * ASTRIDE + p * 4];
        atomicAdd(d1 + 0, a1.x); atomicAdd(d1 + 1, a1.y);
        atomicAdd(d1 + 2, b1v.x); atomicAdd(d1 + 3, b1v.y);
    }
    if (i < end) {
        unsigned e0 = binned[i];
        uint2 u0 = fp[(size_t)((e0 >> 8) << 2) + p];
        float2 a0 = h2f(u0.x), b0 = h2f(u0.y);
        float* d0 = &acc[(int)(e0 & 255) * ASTRIDE + p * 4];
        atomicAdd(d0 + 0, a0.x); atomicAdd(d0 + 1, a0.y);
        atomicAdd(d0 + 2, b0.x); atomicAdd(d0 + 3, b0.y);
    }
    __syncthreads();
    if (L == 1) {
        for (int idx = t; idx < nn * 4; idx += 512) {
            int d = idx >> 2, pp = idx & 3;
            int node = base + d;
            float di = dis[node];
            const float* a = &acc[d * ASTRIDE + pp * 4];
            float4 bv = ((const float4*)bias)[pp];
            float rx = fmaxf(di * a[0] + bv.x, 0.f) * di;   // pre-scaled for layer 2
            float ry = fmaxf(di * a[1] + bv.y, 0.f) * di;
            float rz = fmaxf(di * a[2] + bv.z, 0.f) * di;
            float rw = fmaxf(di * a[3] + bv.w, 0.f) * di;
            uint2 w;
            w.x = pack2(rx, ry);
            w.y = pack2(rz, rw);
            ((uint2*)outp)[(size_t)node * 4 + pp] = w;
        }
    } else {
        for (int idx = t; idx < nn * 2; idx += 512) {
            int d = idx >> 1, h = idx & 1;   // 2 threads/node, 16 cols each
            int node = base + d;
            float di = dis[node];
            float p16[FHID];
#pragma unroll
            for (int c = 0; c < FHID; ++c) p16[c] = di * acc[d * ASTRIDE + c];
            float o[16];
#pragma unroll
            for (int j = 0; j < 16; ++j) {
                int col = h * 16 + j;
                float s = bs[col];
#pragma unroll
                for (int c = 0; c < FHID; ++c) s += p16[c] * wb[c * NACT + col];
                o[j] = s;
            }
            float4* orow = (float4*)outp + (size_t)node * 8 + h * 4;
            orow[0] = make_float4(o[0], o[1], o[2], o[3]);
            orow[1] = make_float4(o[4], o[5], o[6], o[7]);
            orow[2] = make_float4(o[8], o[9], o[10], o[11]);
            orow[3] = make_float4(o[12], o[13], o[14], o[15]);
        }
    }
}

extern "C" void kernel_launch(void* const* d_in, const int* in_sizes, int n_in,
                              void* d_out, int out_size, void* d_ws, size_t ws_size,
                              hipStream_t stream) {
    const float* x  = (const float*)d_in[0];
    const float* W1 = (const float*)d_in[1];
    const float* b1 = (const float*)d_in[2];
    const float* W2 = (const float*)d_in[3];
    const float* b2 = (const float*)d_in[4];
    const int*   ei = (const int*)d_in[5];
    const int E = in_sizes[5] / 2;
    const int n = NNODES;
    const int npad = n + 8;               // keeps fp16 tables 16B-aligned
    const int* src = ei;
    const int* dst = ei + E;
    const int ntiles = (E + TILE - 1) / TILE;

    // floats: dis[n] | featp fp16 [16*npad] | h1p fp16 [16*npad]
    // ints:   bcnt[NB] bptr[NB+1] gcur[NB] | thist[ntiles*NB] ushort | binned[E]
    float* fb    = (float*)d_ws;
    float* dis   = fb;
    __half* featp = (__half*)(fb + (size_t)n);
    __half* h1p   = featp + (size_t)16 * npad;
    int*   ib    = (int*)(h1p + (size_t)16 * npad);
    int*   bcnt  = ib;
    int*   bptr  = ib + NB;
    int*   gcur  = ib + 2 * NB + 1;
    size_t thist_off = (size_t)(3 * NB + 1);
    unsigned short* thist = (unsigned short*)(ib + thist_off);
    size_t thist_ints = ((size_t)ntiles * NB + 1) / 2;
    unsigned* binned = (unsigned*)(ib + thist_off + thist_ints);

    (void)hipMemsetAsync(bcnt, 0, NB * sizeof(int), stream);

    const int B = 256;
    k_coarse<<<ntiles, B, 0, stream>>>(dst, E, bcnt, thist);
    k_scan<<<1, 512, 0, stream>>>(bcnt, bptr, gcur);
    k_bin<<<ntiles, 512, 0, stream>>>(src, dst, E, gcur, thist, binned);
    k_deg<<<NB, B, 0, stream>>>(bptr, binned, dis, n);
    k_xw1<<<(n + 1 + B - 1) / B, B, 0, stream>>>(x, W1, dis, featp, n);
    k_agg<1><<<NB, 512, 0, stream>>>(bptr, binned, dis, featp, nullptr, b1, (void*)h1p, n);
    k_agg<2><<<NB, 512, 0, stream>>>(bptr, binned, dis, h1p, W2, b2, d_out, n);
}

// Round 3
// 244.216 us; speedup vs baseline: 2.9246x; 2.9246x over previous
//
#include <hip/hip_runtime.h>
#include <hip/hip_fp16.h>

// QNetGNN: 2-layer GCN, N=100000, E=3.2M, F: 128 -> 16 -> 32.
// R13 resubmit (R2 bench was an infra failure: "container failed twice",
// no pytest/profile output; source re-audited, no hang/fault candidates).
// Pull pipeline (verified R11 preprocessing) + k_gather restructured from
// 8 lanes/node x uint2 (4 L2 requests per 32B feature row) to 16
// lanes/node x uint4 (2 requests/row, 16B/lane). Theory: gathers are
// L2-request-throughput bound (fp16 table is L2-resident; 12.8M 8B
// requests/layer); halving request count + 2x waves in flight should
// roughly halve the gather phase.

#define NNODES 100000
#define FIN    128
#define FHID   16
#define NACT   32
#define NB     392          // ceil(100000/256) buckets of 256 dst nodes
#define BSH    8            // bucket shift (256 nodes/bucket)
#define BMSK   255
#define TILE   4096
#define PADHEAD 1024        // per-bucket csr padding headroom

// ---- coarse histogram of dst buckets; also store per-tile hist (ushort) ----
__global__ void k_coarse(const int* __restrict__ dst, int E, int* __restrict__ bcnt,
                         unsigned short* __restrict__ thist) {
    __shared__ int hist[NB];
    int t = threadIdx.x;
    int tb = blockIdx.x * TILE;
    int tn = min(TILE, E - tb);
    for (int i = t; i < NB; i += 256) hist[i] = 0;
    __syncthreads();
    for (int i = t; i < tn; i += 256) atomicAdd(&hist[dst[tb + i] >> BSH], 1);
    __syncthreads();
    size_t row = (size_t)blockIdx.x * NB;
    for (int i = t; i < NB; i += 256) {
        int hv = hist[i];
        thist[row + i] = (unsigned short)hv;
        if (hv) atomicAdd(&bcnt[i], hv);
    }
}

// ---- exclusive scan of bcnt -> bptr[0..NB], init gcur (512 thr, NB<=512) ----
__global__ void __launch_bounds__(512) k_scan(
        const int* __restrict__ bcnt, int* __restrict__ bptr,
        int* __restrict__ gcur) {
    __shared__ int part[512];
    int t = threadIdx.x;
    int c = (t < NB) ? bcnt[t] : 0;
    part[t] = c;
    __syncthreads();
    for (int d = 1; d < 512; d <<= 1) {
        int v = part[t];
        int add = (t >= d) ? part[t - d] : 0;
        __syncthreads();
        part[t] = v + add;
        __syncthreads();
    }
    int excl = t ? part[t - 1] : 0;
    if (t < NB) { bptr[t] = excl; gcur[t] = excl; }
    if (t == NB) bptr[NB] = excl;      // total (c==0 for t>=NB)
}

// ---- bin: staged LDS counting sort, precomputed global dests, 512 thr ----
__global__ void __launch_bounds__(512) k_bin(
        const int* __restrict__ src, const int* __restrict__ dst, int E,
        int* __restrict__ gcur, const unsigned short* __restrict__ thist,
        unsigned* __restrict__ binned) {
    __shared__ unsigned staged[TILE];     // 16 KB
    __shared__ int gscat[TILE];           // 16 KB
    __shared__ int lstart[NB + 1];
    __shared__ int lcur[NB];
    __shared__ int gbase[NB];
    __shared__ int part[512];
    int t = threadIdx.x;
    int tb = blockIdx.x * TILE;
    int tn = min(TILE, E - tb);
    size_t row = (size_t)blockIdx.x * NB;
    int c = (t < NB) ? (int)thist[row + t] : 0;
    part[t] = c;
    __syncthreads();
    for (int d = 1; d < 512; d <<= 1) {
        int v = part[t];
        int add = (t >= d) ? part[t - d] : 0;
        __syncthreads();
        part[t] = v + add;
        __syncthreads();
    }
    int excl = t ? part[t - 1] : 0;
    if (t < NB) { lstart[t] = excl; lcur[t] = excl; }
    if (t == NB) lstart[NB] = excl;
    __syncthreads();
    if (t < NB) gbase[t] = (c > 0) ? atomicAdd(&gcur[t], c) : 0;
    __syncthreads();
    for (int i = t; i < tn; i += 512) {
        int d = dst[tb + i], sv = src[tb + i];
        int b = d >> BSH;
        int pos = atomicAdd(&lcur[b], 1);
        staged[pos] = ((unsigned)sv << BSH) | (unsigned)(d & BMSK);
        gscat[pos] = gbase[b] + (pos - lstart[b]);
    }
    __syncthreads();
    for (int j = t; j < tn; j += 512) binned[gscat[j]] = staged[j];
}

// ---- per-bucket (256 nodes): degrees -> dis; padded CSR (entries src*4) ----
// 1024 threads: grid is fixed at NB blocks, taller blocks add waves.
__global__ void __launch_bounds__(1024) k_csr(
        const int* __restrict__ bptr, const unsigned* __restrict__ binned,
        float* __restrict__ dis, int* __restrict__ rowptr,
        int* __restrict__ plen4, int* __restrict__ csr, int n) {
    __shared__ int cnt[256];
    __shared__ int pl[256];
    __shared__ int part[256];
    __shared__ int lbase[256];
    __shared__ int lcur[256];
    int t = threadIdx.x;
    int bk = blockIdx.x;
    int beg = bptr[bk], end = bptr[bk + 1];
    int rbase = (beg & ~3) + PADHEAD * bk;   // 16B-aligned, padding headroom
    if (t < 256) cnt[t] = 0;
    __syncthreads();
    for (int i = beg + t; i < end; i += 1024) atomicAdd(&cnt[binned[i] & BMSK], 1);
    __syncthreads();
    if (t < 256) { pl[t] = (cnt[t] + 3) & ~3; part[t] = pl[t]; }
    __syncthreads();
    for (int d = 1; d < 256; d <<= 1) {
        int v = 0;
        if (t < 256) { v = part[t]; if (t >= d) v += part[t - d]; }
        __syncthreads();
        if (t < 256) part[t] = v;
        __syncthreads();
    }
    if (t < 256) {
        lbase[t] = t ? part[t - 1] : 0;
        lcur[t] = 0;
        int node = (bk << BSH) + t;
        if (node < n) {
            int rp = rbase + lbase[t];
            rowptr[node] = rp;
            plen4[node] = pl[t] >> 2;
            dis[node] = rsqrtf((float)cnt[t] + 1.0f);
            for (int k = cnt[t]; k < pl[t]; ++k) csr[rp + k] = n << 2;  // dummy pad
        }
    }
    __syncthreads();
    for (int i = beg + t; i < end; i += 1024) {
        unsigned e = binned[i];
        int dloc = e & BMSK;
        int pos = atomicAdd(&lcur[dloc], 1);
        csr[rbase + lbase[dloc] + pos] = (int)(e >> BSH) << 2;   // pre-shifted
    }
}

#define FMA4(A, S, W) { (A).x += (S) * (W).x; (A).y += (S) * (W).y; \
                        (A).z += (S) * (W).z; (A).w += (S) * (W).w; }

__device__ __forceinline__ unsigned pack2(float a, float b) {
    __half2 h = __floats2half2_rn(a, b);
    return *reinterpret_cast<unsigned*>(&h);
}

__device__ __forceinline__ float2 h2f(unsigned u) {
    return __half22float2(*reinterpret_cast<__half2*>(&u));
}

// ---- featp = fp16((x @ W1) * dis); row n = zeros ----
__global__ void k_xw1(const float* __restrict__ x, const float* __restrict__ W1,
                      const float* __restrict__ dis, __half* __restrict__ featp, int n) {
    __shared__ float w[FIN * FHID];   // 8 KB, row-major [128][16]
    for (int i = threadIdx.x; i < FIN * FHID; i += blockDim.x) w[i] = W1[i];
    __syncthreads();
    int r = blockIdx.x * blockDim.x + threadIdx.x;
    if (r > n) return;
    uint4* hr = (uint4*)(featp + (size_t)r * FHID);   // 32 B row = 2 uint4
    if (r == n) {
        uint4 z = make_uint4(0u, 0u, 0u, 0u);
        hr[0] = z; hr[1] = z;
        return;
    }
    const float4* xr = (const float4*)(x + (long long)r * FIN);
    const float4* w4 = (const float4*)w;      // [128][4] float4s
    float4 a0 = make_float4(0.f, 0.f, 0.f, 0.f), a1 = a0, a2 = a0, a3 = a0;
#pragma unroll 8
    for (int k4 = 0; k4 < FIN / 4; ++k4) {
        float4 xv = xr[k4];
        int kb = k4 * 16;
        FMA4(a0, xv.x, w4[kb + 0]);  FMA4(a1, xv.x, w4[kb + 1]);
        FMA4(a2, xv.x, w4[kb + 2]);  FMA4(a3, xv.x, w4[kb + 3]);
        FMA4(a0, xv.y, w4[kb + 4]);  FMA4(a1, xv.y, w4[kb + 5]);
        FMA4(a2, xv.y, w4[kb + 6]);  FMA4(a3, xv.y, w4[kb + 7]);
        FMA4(a0, xv.z, w4[kb + 8]);  FMA4(a1, xv.z, w4[kb + 9]);
        FMA4(a2, xv.z, w4[kb + 10]); FMA4(a3, xv.z, w4[kb + 11]);
        FMA4(a0, xv.w, w4[kb + 12]); FMA4(a1, xv.w, w4[kb + 13]);
        FMA4(a2, xv.w, w4[kb + 14]); FMA4(a3, xv.w, w4[kb + 15]);
    }
    float d = dis[r];
    uint4 w0, w1;
    w0.x = pack2(a0.x * d, a0.y * d); w0.y = pack2(a0.z * d, a0.w * d);
    w0.z = pack2(a1.x * d, a1.y * d); w0.w = pack2(a1.z * d, a1.w * d);
    w1.x = pack2(a2.x * d, a2.y * d); w1.y = pack2(a2.z * d, a2.w * d);
    w1.z = pack2(a3.x * d, a3.y * d); w1.w = pack2(a3.z * d, a3.w * d);
    hr[0] = w0; hr[1] = w1;
}

// accumulate 8 fp16 (one uint4 = 16B half-row) into a0/a1
#define ACC8F(U) { float2 f_; \
    f_ = h2f((U).x); a0.x += f_.x; a0.y += f_.y; \
    f_ = h2f((U).y); a0.z += f_.x; a0.w += f_.y; \
    f_ = h2f((U).z); a1.x += f_.x; a1.y += f_.y; \
    f_ = h2f((U).w); a1.z += f_.x; a1.w += f_.y; }

// ---- gather: 16 lanes/node, uint4 (16B) feature loads, shfl reduce ----
// lane l = t&15: p = l&1 selects 16B half-row, grp = l>>1 (8 groups) splits
// the int4 csr groups. 2 L2 requests per 32B row instead of 4.
// L==1: h1p = fp16(relu(di*sum + b1)*di)   [N,16]
// L==2: out = (di*sum) @ W2 + b2           [N,32] fp32 (W2 fused)
template <int L>
__global__ void __launch_bounds__(256, 6) k_gather(
        const int* __restrict__ rowptr, const int* __restrict__ plen4,
        const int* __restrict__ csr, const float* __restrict__ dis,
        const __half* __restrict__ featp, const float* __restrict__ W2,
        const float* __restrict__ bias, void* __restrict__ outp, int n) {
    __shared__ float wb[FHID * NACT];
    __shared__ float bs[NACT];
    if (L == 2) {
        for (int i = threadIdx.x; i < FHID * NACT; i += 256) wb[i] = W2[i];
        if (threadIdx.x < NACT) bs[threadIdx.x] = bias[threadIdx.x];
        __syncthreads();
    }
    int t = blockIdx.x * blockDim.x + threadIdx.x;
    int node = t >> 4, l = t & 15, p = l & 1, grp = l >> 1;
    if (node > n) return;
    const uint4* fp4 = (const uint4*)featp;   // 2 uint4 (16B halves) per row
    if (node == n) {
        if (L == 1 && l < 2) ((uint4*)outp)[(size_t)node * 2 + p] = make_uint4(0u, 0u, 0u, 0u);
        return;
    }
    float4 a0 = make_float4(0.f, 0.f, 0.f, 0.f), a1 = a0;
    if (grp == 7) {   // self loop (pre-scaled); grp 7 is idle when it<8
        uint4 u = fp4[((size_t)node << 1) + p];
        ACC8F(u);
    }
    int beg = rowptr[node];
    int it = plen4[node];
    const int4* cp = (const int4*)(csr + beg);
    for (int k = grp; k < it; k += 8) {
        int4 s = cp[k];                        // entries are src*4
        uint4 u0 = fp4[(size_t)((unsigned)s.x >> 1) + p];
        uint4 u1 = fp4[(size_t)((unsigned)s.y >> 1) + p];
        uint4 u2 = fp4[(size_t)((unsigned)s.z >> 1) + p];
        uint4 u3 = fp4[(size_t)((unsigned)s.w >> 1) + p];
        ACC8F(u0); ACC8F(u1); ACC8F(u2); ACC8F(u3);
    }
    // reduce over grp bits (lane^2, lane^4, lane^8): all 16 lanes end with
    // the full sum for their half-row p
#pragma unroll
    for (int m = 2; m <= 8; m <<= 1) {
        a0.x += __shfl_xor(a0.x, m, 64);
        a0.y += __shfl_xor(a0.y, m, 64);
        a0.z += __shfl_xor(a0.z, m, 64);
        a0.w += __shfl_xor(a0.w, m, 64);
        a1.x += __shfl_xor(a1.x, m, 64);
        a1.y += __shfl_xor(a1.y, m, 64);
        a1.z += __shfl_xor(a1.z, m, 64);
        a1.w += __shfl_xor(a1.w, m, 64);
    }
    float di = dis[node];
    if (L == 1) {
        if (l < 2) {    // 2 lanes write the 2 x 16B halves of the fp16 row
            const float4* b4 = (const float4*)bias;
            float4 bv0 = b4[p * 2], bv1 = b4[p * 2 + 1];
            float r0 = fmaxf(di * a0.x + bv0.x, 0.f) * di;   // pre-scaled for layer 2
            float r1 = fmaxf(di * a0.y + bv0.y, 0.f) * di;
            float r2 = fmaxf(di * a0.z + bv0.z, 0.f) * di;
            float r3 = fmaxf(di * a0.w + bv0.w, 0.f) * di;
            float r4 = fmaxf(di * a1.x + bv1.x, 0.f) * di;
            float r5 = fmaxf(di * a1.y + bv1.y, 0.f) * di;
            float r6 = fmaxf(di * a1.z + bv1.z, 0.f) * di;
            float r7 = fmaxf(di * a1.w + bv1.w, 0.f) * di;
            uint4 w;
            w.x = pack2(r0, r1); w.y = pack2(r2, r3);
            w.z = pack2(r4, r5); w.w = pack2(r6, r7);
            ((uint4*)outp)[(size_t)node * 2 + p] = w;
        }
    } else {
        // gather the full 16-float hidden row (scaled by di) via shfl
        int base16 = (threadIdx.x & 63) & ~15;
        float v0 = di * a0.x, v1 = di * a0.y, v2 = di * a0.z, v3 = di * a0.w;
        float v4 = di * a1.x, v5 = di * a1.y, v6 = di * a1.z, v7 = di * a1.w;
        float p16[16];
        p16[0]  = __shfl(v0, base16,     64); p16[8]  = __shfl(v0, base16 + 1, 64);
        p16[1]  = __shfl(v1, base16,     64); p16[9]  = __shfl(v1, base16 + 1, 64);
        p16[2]  = __shfl(v2, base16,     64); p16[10] = __shfl(v2, base16 + 1, 64);
        p16[3]  = __shfl(v3, base16,     64); p16[11] = __shfl(v3, base16 + 1, 64);
        p16[4]  = __shfl(v4, base16,     64); p16[12] = __shfl(v4, base16 + 1, 64);
        p16[5]  = __shfl(v5, base16,     64); p16[13] = __shfl(v5, base16 + 1, 64);
        p16[6]  = __shfl(v6, base16,     64); p16[14] = __shfl(v6, base16 + 1, 64);
        p16[7]  = __shfl(v7, base16,     64); p16[15] = __shfl(v7, base16 + 1, 64);
        int col = l * 2;                 // each lane computes 2 of 32 columns
        float s0 = bs[col], s1 = bs[col + 1];
#pragma unroll
        for (int c = 0; c < FHID; ++c) {
            s0 += p16[c] * wb[c * NACT + col];
            s1 += p16[c] * wb[c * NACT + col + 1];
        }
        ((float2*)outp)[(size_t)node * 16 + l] = make_float2(s0, s1);
    }
}

extern "C" void kernel_launch(void* const* d_in, const int* in_sizes, int n_in,
                              void* d_out, int out_size, void* d_ws, size_t ws_size,
                              hipStream_t stream) {
    const float* x  = (const float*)d_in[0];
    const float* W1 = (const float*)d_in[1];
    const float* b1 = (const float*)d_in[2];
    const float* W2 = (const float*)d_in[3];
    const float* b2 = (const float*)d_in[4];
    const int*   ei = (const int*)d_in[5];
    const int E = in_sizes[5] / 2;
    const int n = NNODES;
    const int npad = n + 8;               // keeps fp16 tables 16B-aligned
    const int* src = ei;
    const int* dst = ei + E;
    const int ntiles = (E + TILE - 1) / TILE;

    // floats: dis[n] | featp fp16 [16*npad] | h1p fp16 [16*npad]
    // ints:   bcnt[NB] bptr[NB+1] gcur[NB] rowptr[n] plen4[n]
    //         | thist[ntiles*NB] ushort | binned[E] | csr[E+PADHEAD*NB+64]
    float* fb    = (float*)d_ws;
    float* dis   = fb;
    __half* featp = (__half*)(fb + (size_t)n);
    __half* h1p   = featp + (size_t)16 * npad;
    int*   ib    = (int*)(h1p + (size_t)16 * npad);
    int*   bcnt  = ib;
    int*   bptr  = ib + NB;
    int*   gcur  = ib + 2 * NB + 1;
    int*   rowptr = ib + 3 * NB + 1;
    int*   plen4 = rowptr + n;
    size_t thist_off = (size_t)(3 * NB + 1) + 2 * (size_t)n;          // in ints
    unsigned short* thist = (unsigned short*)(ib + thist_off);
    size_t thist_ints = ((size_t)ntiles * NB + 1) / 2;
    size_t binned_off = thist_off + thist_ints;
    unsigned* binned = (unsigned*)(ib + binned_off);
    size_t csr_off = (binned_off + (size_t)E + 3) & ~(size_t)3;       // 16B-align
    int*   csr   = ib + csr_off;

    (void)hipMemsetAsync(bcnt, 0, NB * sizeof(int), stream);

    const int B = 256;
    k_coarse<<<ntiles, B, 0, stream>>>(dst, E, bcnt, thist);
    k_scan<<<1, 512, 0, stream>>>(bcnt, bptr, gcur);
    k_bin<<<ntiles, 512, 0, stream>>>(src, dst, E, gcur, thist, binned);
    k_csr<<<NB, 1024, 0, stream>>>(bptr, binned, dis, rowptr, plen4, csr, n);
    k_xw1<<<(n + 1 + B - 1) / B, B, 0, stream>>>(x, W1, dis, featp, n);
    k_gather<1><<<((n + 1) * 16 + B - 1) / B, B, 0, stream>>>(rowptr, plen4, csr, dis, featp,
                                                              nullptr, b1, (void*)h1p, n);
    k_gather<2><<<((n + 1) * 16 + B - 1) / B, B, 0, stream>>>(rowptr, plen4, csr, dis, h1p,
                                                              W2, b2, d_out, n);
}